// Round 15
// baseline (158.668 us; speedup 1.0000x reference)
//
#include <hip/hip_runtime.h>

// PointConv: B=4, N=16384, K=32, F=64
// out[p,f] = sum_k ( lrelu(rel(p,k) @ W1 + b1) @ W2 + b2 )[f] * x[idx[p,k], f]
//
// Round 19: the LAST untested corner. Nine causal hypotheses produced their
// predicted counter deltas (VALU -14%, DS-ops -60%, FETCH -45% r18, occ +50%,
// pipeline x2 depth) with ZERO duration response — but every ILP/hoist probe
// ran at (256,2)=128 arch VGPRs (measured law: budget = 256/waves_per_EU)
// while the designs needed 160-230 regs: the compiler rematerialized them
// away, so deep-pipeline-with-registers was never actually measured.
// This round: (256,1) -> 256 arch VGPRs. One wave/SIMD (zero TLP) but the
// full design finally fits: w1r 64 + bfrag 32 + xvA/B 64 + acc 32 + state
// ~= 235 <= 256. The 2-deep in-wave pipeline does ALL latency hiding.
// Single variable vs r18 (which measured 70.4us rocprof): launch bounds.
// Tripwires: VGPR stays ~128 -> law wrong, probe void; WRITE>25MB -> spill;
// dur >= 65us -> plateau confirmed structural from BOTH ends (max-TLP and
// max-ILP), declare ceiling with r11/r18 (137.3us harness) as the answer.

#define NPTS   16384
#define KNB    32
#define F      64
#define BATCH  4
#define LOG2N  14
#define WPTS   8

typedef _Float16 h2     __attribute__((ext_vector_type(2)));
typedef _Float16 h8     __attribute__((ext_vector_type(8)));
typedef float    f32x16 __attribute__((ext_vector_type(16)));

__global__ __launch_bounds__(256, 1) void pointconv_mfma(
    const float* __restrict__ x,
    const float* __restrict__ pos,
    const int*   __restrict__ idx,
    const float* __restrict__ W1,
    const float* __restrict__ b1,
    const float* __restrict__ W2,
    const float* __restrict__ b2,
    float*       __restrict__ out)
{
    // w1p[g/2] = {wx,wx', wy,wy', wz,wz', b1,b1'} for g-pair (f16)
    __shared__ __align__(16) _Float16 w1p[32][8];
    // w2f[hf][t][c][m][j] = f16(W2[16t+8hf+j][2m+c]) — fragment-ordered,
    // lanes read consecutive 16B blocks -> conflict-free ds_read_b128
    __shared__ __align__(16) _Float16 w2f[2][4][2][32][8];

    const int tid = threadIdx.x;
    if (tid < 32) {
        const int g = 2 * tid;
        w1p[tid][0] = (_Float16)W1[0 * F + g]; w1p[tid][1] = (_Float16)W1[0 * F + g + 1];
        w1p[tid][2] = (_Float16)W1[1 * F + g]; w1p[tid][3] = (_Float16)W1[1 * F + g + 1];
        w1p[tid][4] = (_Float16)W1[2 * F + g]; w1p[tid][5] = (_Float16)W1[2 * F + g + 1];
        w1p[tid][6] = (_Float16)b1[g];         w1p[tid][7] = (_Float16)b1[g + 1];
    }
#pragma unroll
    for (int r = 0; r < 16; ++r) {             // 4096 elems, coalesced global read
        const int e = r * 256 + tid;           // e = g*64 + f
        const int g = e >> 6, f = e & 63;
        w2f[(g >> 3) & 1][g >> 4][f & 1][f >> 1][g & 7] = (_Float16)W2[e];
    }
    __syncthreads();

    const int lane = tid & 63;
    const int wv   = tid >> 6;
    const int m    = lane & 31;   // MFMA row (neighbor slot) / f-pair index
    const int hf   = lane >> 5;   // k-half of A/B fragments
    const int voff = hf << 4;     // bpermute byte base (source lane 4*hf + rA)

    // ---- loop-invariant fragments -> registers (NOW they fit: 256 budget) ----
    h8 w1r[16];
#pragma unroll
    for (int t = 0; t < 4; ++t)
#pragma unroll
        for (int jj = 0; jj < 4; ++jj)
            w1r[4 * t + jj] = *(const h8*)&w1p[8 * t + 4 * hf + jj][0];
    h8 bfrag[4][2];
#pragma unroll
    for (int t = 0; t < 4; ++t)
#pragma unroll
        for (int c = 0; c < 2; ++c)
            bfrag[t][c] = *(const h8*)&w2f[hf][t][c][m][0];

    const float2 b2v = *(const float2*)(b2 + 2 * m);

    // ---- batch-pinned XCD swizzle (kept from r18: FETCH 92->51MB) ----
    const int bid    = blockIdx.x;
    const int xcd    = bid & 7;
    const int slot   = bid >> 3;                 // 0..255
    const int batch  = xcd >> 1;                 // 0..3
    const int within = slot * 2 + (xcd & 1);     // 0..511 inside batch

    const int p0   = batch * NPTS + within * (4 * WPTS) + wv * WPTS;
    const int p0_s = __builtin_amdgcn_readfirstlane(p0);
    const int base = (p0_s >> LOG2N) << LOG2N;                     // b*N
    const uint32_t m2 = 2u * (uint32_t)m;                          // f-pair offset

    const h2 c01 = { (_Float16)0.1f, (_Float16)0.1f };

    // ---- prologue: point p0's rel-pos raw loads, x-gathers; jm for p0+1 ----
    float2 xvA[16], xvB[16];
    float  rlA[6], rlB[6];        // {nbr x,y,z, own x,y,z} raw loads, sub at use
    int    jmA = 0, jmB = 0;      // idx[p][m] pipeline (2 deep)
    {
        const int jm0 = idx[(uint32_t)(p0_s * KNB) + (uint32_t)m];
#pragma unroll
        for (int reg = 0; reg < 16; ++reg) {
            const int rA = (reg & 3) + ((reg >> 2) << 3);
            const int jk = __builtin_amdgcn_ds_bpermute(voff + 4 * rA, jm0);
            const uint32_t xo = ((uint32_t)(base + jk) << 6) + m2;
            xvA[reg] = *(const float2*)(x + xo);
        }
        const uint32_t nr3 = 3u * (uint32_t)(base + jm0);
        const uint32_t pp3 = 3u * (uint32_t)p0_s;
        rlA[0] = pos[nr3];     rlA[1] = pos[nr3 + 1]; rlA[2] = pos[nr3 + 2];
        rlA[3] = pos[pp3];     rlA[4] = pos[pp3 + 1]; rlA[5] = pos[pp3 + 2];
        if (WPTS > 1) jmA = idx[(uint32_t)((p0_s + 1) * KNB) + (uint32_t)m];
    }

    // Per iteration (output point p = p0+I):
    //   JM_CUR = idx row p+1 (loaded iter I-1)   JM_NXT <- idx row p+2
    //   RL_CUR = pos raw loads for p (iter I-1)  RL_NXT <- pos loads for p+1
    //   XV_CUR = x rows for p (iter I-1)         XV_NXT <- x rows for p+1
#define POINT_BODY(XV_CUR, XV_NXT, JM_CUR, JM_NXT, RL_CUR, RL_NXT, I)         \
    {                                                                         \
        const int p_s = p0_s + (I);                                           \
        /* (1) idx row p+2, per-lane, no deps */                              \
        if ((I) + 2 < WPTS)                                                   \
            JM_NXT = idx[(uint32_t)((p_s + 2) * KNB) + (uint32_t)m];          \
        /* (2) pos raw loads for p+1 (JM_CUR is an iteration old: ready) */   \
        if ((I) + 1 < WPTS) {                                                 \
            const uint32_t nr3 = 3u * (uint32_t)(base + JM_CUR);              \
            const uint32_t pp3 = 3u * (uint32_t)(p_s + 1);                    \
            RL_NXT[0] = pos[nr3];     RL_NXT[1] = pos[nr3 + 1];               \
            RL_NXT[2] = pos[nr3 + 2];                                         \
            RL_NXT[3] = pos[pp3];     RL_NXT[4] = pos[pp3 + 1];               \
            RL_NXT[5] = pos[pp3 + 2];                                         \
        }                                                                     \
        /* (3) x-gathers for p+1: rows from JM_CUR via bpermute, 32b offs */  \
        if ((I) + 1 < WPTS) {                                                 \
            _Pragma("unroll")                                                 \
            for (int reg = 0; reg < 16; ++reg) {                              \
                const int rA = (reg & 3) + ((reg >> 2) << 3);                 \
                const int jk = __builtin_amdgcn_ds_bpermute(voff + 4 * rA, JM_CUR); \
                const uint32_t xo = ((uint32_t)(base + jk) << 6) + m2;        \
                XV_NXT[reg] = *(const float2*)(x + xo);                       \
            }                                                                 \
        }                                                                     \
        /* (4) MFMA phase for p (RL_CUR loads are an iteration old) */        \
        const float rx = RL_CUR[3] - RL_CUR[0];                               \
        const float ry = RL_CUR[4] - RL_CUR[1];                               \
        const float rz = RL_CUR[5] - RL_CUR[2];                               \
        f32x16 acc0, acc1;                                                    \
        _Pragma("unroll")                                                     \
        for (int r = 0; r < 16; ++r) { acc0[r] = b2v.x; acc1[r] = b2v.y; }    \
        const h2 rxp = { (_Float16)rx, (_Float16)rx };                        \
        const h2 ryp = { (_Float16)ry, (_Float16)ry };                        \
        const h2 rzp = { (_Float16)rz, (_Float16)rz };                        \
        _Pragma("unroll")                                                     \
        for (int t = 0; t < 4; ++t) {                                         \
            h8 af;                                                            \
            _Pragma("unroll")                                                 \
            for (int jj = 0; jj < 4; ++jj) {                                  \
                const h8 w = w1r[4 * t + jj];                                 \
                const h2 wx = __builtin_shufflevector(w, w, 0, 1);            \
                const h2 wy = __builtin_shufflevector(w, w, 2, 3);            \
                const h2 wz = __builtin_shufflevector(w, w, 4, 5);            \
                const h2 bb = __builtin_shufflevector(w, w, 6, 7);            \
                h2 hv = bb + rxp * wx;                                        \
                hv = hv + ryp * wy;                                           \
                hv = hv + rzp * wz;                                           \
                hv = __builtin_elementwise_max(hv, hv * c01);                 \
                af[2 * jj]     = hv[0];                                       \
                af[2 * jj + 1] = hv[1];                                       \
            }                                                                 \
            acc0 = __builtin_amdgcn_mfma_f32_32x32x16_f16(af, bfrag[t][0], acc0, 0, 0, 0); \
            acc1 = __builtin_amdgcn_mfma_f32_32x32x16_f16(af, bfrag[t][1], acc1, 0, 0, 0); \
        }                                                                     \
        /* (5) epilogue: consume XV_CUR (issued one iteration ago) */         \
        float s0 = 0.f, s1 = 0.f;                                             \
        _Pragma("unroll")                                                     \
        for (int reg = 0; reg < 16; ++reg) {                                  \
            s0 = fmaf(acc0[reg], XV_CUR[reg].x, s0);                          \
            s1 = fmaf(acc1[reg], XV_CUR[reg].y, s1);                          \
        }                                                                     \
        s0 += __shfl_xor(s0, 32);                                             \
        s1 += __shfl_xor(s1, 32);                                             \
        if (hf == 0)                                                          \
            *(float2*)(out + (uint32_t)(p_s * F) + m2) = make_float2(s0, s1); \
    }

#pragma unroll 1
    for (int io = 0; io < WPTS; io += 2) {
        POINT_BODY(xvA, xvB, jmA, jmB, rlA, rlB, io);
        POINT_BODY(xvB, xvA, jmB, jmA, rlB, rlA, io + 1);
    }
#undef POINT_BODY
}

extern "C" void kernel_launch(void* const* d_in, const int* in_sizes, int n_in,
                              void* d_out, int out_size, void* d_ws, size_t ws_size,
                              hipStream_t stream) {
    const float* x   = (const float*)d_in[0];
    const float* pos = (const float*)d_in[1];
    const int*   idx = (const int*)  d_in[2];
    const float* W1  = (const float*)d_in[3];
    const float* b1  = (const float*)d_in[4];
    const float* W2  = (const float*)d_in[5];
    const float* b2  = (const float*)d_in[6];
    float* out = (float*)d_out;

    dim3 grid((BATCH * NPTS) / (4 * WPTS));   // 2048 blocks, % 8 == 0
    dim3 block(256);
    pointconv_mfma<<<grid, block, 0, stream>>>(x, pos, idx, W1, b1, W2, b2, out);
}